// Round 9
// baseline (227.579 us; speedup 1.0000x reference)
//
#include <hip/hip_runtime.h>
#include <hip/hip_bf16.h>

#define TOPK 30
#define NAT 14
#define EDGE_IN 3152   // 16 PE + 14*14*16 RBF
#define KPAD 3168      // padded to 99 chunks of 32
#define NCHUNK 99
#define EPB 32         // edges per k_edge block
#define KSPL 4         // K-split streams per block
#define SMAX 25        // max chunks per stream (25,25,25,24)

typedef __attribute__((ext_vector_type(8))) short bf16x8;
typedef __attribute__((ext_vector_type(4))) float f32x4;

typedef const __attribute__((address_space(1))) void* gptr_t;
typedef __attribute__((address_space(3))) void* lptr_t;

__device__ __forceinline__ unsigned short f2bf(float f) {
    union { float f; unsigned u; } v; v.f = f;
    unsigned r = v.u + 0x7FFF + ((v.u >> 16) & 1);   // RNE
    return (unsigned short)(r >> 16);
}
__device__ __forceinline__ float bf2f(unsigned short h) {
    union { unsigned u; float f; } v; v.u = ((unsigned)h) << 16;
    return v.f;
}
__device__ __forceinline__ short cvtbf(float f) {     // compiler bf16 cast (G: m240)
    __hip_bfloat16 h = __float2bfloat16(f);
    return *reinterpret_cast<short*>(&h);
}

// ---------------- Xa = [N, Ca, C, O, Cb, sc9] ----------------
__global__ void k_prep(const float* __restrict__ X, float* __restrict__ Xa, int N) {
    int i = blockIdx.x * blockDim.x + threadIdx.x;
    if (i >= N) return;
    const float* xi = X + (size_t)i * NAT * 3;
    float* xo = Xa + (size_t)i * NAT * 3;
    float Nx = xi[0], Ny = xi[1], Nz = xi[2];
    float Ax = xi[3], Ay = xi[4], Az = xi[5];
    float Cx = xi[6], Cy = xi[7], Cz = xi[8];
    float bx = Ax - Nx, by = Ay - Ny, bz = Az - Nz;
    float cx = Cx - Ax, cy = Cy - Ay, cz = Cz - Az;
    float ax = by * cz - bz * cy;
    float ay = bz * cx - bx * cz;
    float az = bx * cy - by * cx;
    float Cbx = -0.58273431f * ax + 0.56802827f * bx - 0.54067466f * cx + Ax;
    float Cby = -0.58273431f * ay + 0.56802827f * by - 0.54067466f * cy + Ay;
    float Cbz = -0.58273431f * az + 0.56802827f * bz - 0.54067466f * cz + Az;
#pragma unroll
    for (int a = 0; a < 4; a++) { xo[a*3] = xi[a*3]; xo[a*3+1] = xi[a*3+1]; xo[a*3+2] = xi[a*3+2]; }
    xo[12] = Cbx; xo[13] = Cby; xo[14] = Cbz;
#pragma unroll
    for (int a = 5; a < 14; a++) { xo[a*3] = xi[a*3]; xo[a*3+1] = xi[a*3+1]; xo[a*3+2] = xi[a*3+2]; }
}

// ---------------- Wt[c][k] = bf16(edge_w[k][c]), zero-padded to KPAD ----------------
__global__ void k_wt(const float* __restrict__ W, unsigned short* __restrict__ Wt) {
    __shared__ unsigned short tile[32][33];
    int kb = blockIdx.x * 32, cb = blockIdx.y * 32;
    int tx = threadIdx.x, ty = threadIdx.y;   // (32,8)
#pragma unroll
    for (int r = 0; r < 32; r += 8) {
        int k = kb + ty + r;
        float v = (k < EDGE_IN) ? W[(size_t)k * 128 + cb + tx] : 0.f;
        tile[ty + r][tx] = f2bf(v);
    }
    __syncthreads();
#pragma unroll
    for (int r = 0; r < 32; r += 8)
        Wt[(size_t)(cb + ty + r) * KPAD + kb + tx] = tile[tx][ty + r];
}

// ---------------- exact stable KNN in FLOAT64 (proven r3-r6 version) ----------------
__global__ __launch_bounds__(256) void k_knn(const float* __restrict__ X, const float* __restrict__ mask,
                                             int* __restrict__ Eidx, float* __restrict__ outI, int N) {
    __shared__ double sD[1024];
    __shared__ double sMax[4];
    __shared__ double sBd[4];
    __shared__ int    sBi[4];
    int i = blockIdx.x, t = threadIdx.x;
    double mi = (double)mask[i];
    double xx = (double)X[((size_t)i * NAT + 1) * 3 + 0];
    double xy = (double)X[((size_t)i * NAT + 1) * 3 + 1];
    double xz = (double)X[((size_t)i * NAT + 1) * 3 + 2];
    double lmax = -1.0;
    for (int j = t; j < N; j += 256) {
        double dx = xx - (double)X[((size_t)j * NAT + 1) * 3 + 0];
        double dy = xy - (double)X[((size_t)j * NAT + 1) * 3 + 1];
        double dz = xz - (double)X[((size_t)j * NAT + 1) * 3 + 2];
        double s = ((dx * dx + dy * dy) + dz * dz) + 1e-6;
        double d = (mi * (double)mask[j]) * sqrt(s);
        sD[j] = d;
        lmax = fmax(lmax, d);
    }
#pragma unroll
    for (int m = 32; m; m >>= 1) lmax = fmax(lmax, __shfl_xor(lmax, m));
    if ((t & 63) == 0) sMax[t >> 6] = lmax;
    __syncthreads();
    double Dmax = fmax(fmax(sMax[0], sMax[1]), fmax(sMax[2], sMax[3]));
    for (int j = t; j < N; j += 256) {
        double m2 = mi * (double)mask[j];
        sD[j] = sD[j] + 2.0 * (1.0 - m2) * Dmax;
    }
    __syncthreads();
    for (int s = 0; s < TOPK; s++) {
        double bd = 1e300;
        int bi = 0x7FFFFFFF;
        for (int j = t; j < N; j += 256) {
            double d = sD[j];
            if (d < bd || (d == bd && j < bi)) { bd = d; bi = j; }
        }
#pragma unroll
        for (int m = 32; m; m >>= 1) {
            double od = __shfl_xor(bd, m);
            int oi = __shfl_xor(bi, m);
            if (od < bd || (od == bd && oi < bi)) { bd = od; bi = oi; }
        }
        if ((t & 63) == 0) { sBd[t >> 6] = bd; sBi[t >> 6] = bi; }
        __syncthreads();
        if (t == 0) {
            double d0 = sBd[0]; int i0 = sBi[0];
#pragma unroll
            for (int w = 1; w < 4; w++) {
                if (sBd[w] < d0 || (sBd[w] == d0 && sBi[w] < i0)) { d0 = sBd[w]; i0 = sBi[w]; }
            }
            Eidx[(size_t)i * TOPK + s] = i0;
            outI[(size_t)i * TOPK + s] = (float)i0;
            sD[i0] = 1e300;
        }
        __syncthreads();
    }
}

// ---------------- node: onehot-gather + matvec + LN (one wave per residue) ----------------
__global__ __launch_bounds__(64) void k_node(const int* __restrict__ S, const float* __restrict__ BB,
                                             const float* __restrict__ W, const float* __restrict__ nb,
                                             const float* __restrict__ g, const float* __restrict__ be,
                                             float* __restrict__ outV, int N) {
    int i = blockIdx.x, t = threadIdx.x;
    int s = S[i];
    float b0 = BB[i*6], b1 = BB[i*6+1], b2 = BB[i*6+2], b3 = BB[i*6+3], b4 = BB[i*6+4], b5 = BB[i*6+5];
    int t2 = t + 64;
    float x0 = W[(size_t)s*128 + t] + nb[t]
             + b0*W[21*128+t] + b1*W[22*128+t] + b2*W[23*128+t]
             + b3*W[24*128+t] + b4*W[25*128+t] + b5*W[26*128+t];
    float x1 = W[(size_t)s*128 + t2] + nb[t2]
             + b0*W[21*128+t2] + b1*W[22*128+t2] + b2*W[23*128+t2]
             + b3*W[24*128+t2] + b4*W[25*128+t2] + b5*W[26*128+t2];
    float sum = x0 + x1;
#pragma unroll
    for (int m = 32; m; m >>= 1) sum += __shfl_xor(sum, m);
    float mean = sum * (1.f / 128.f);
    float d0 = x0 - mean, d1 = x1 - mean;
    float vs = d0*d0 + d1*d1;
#pragma unroll
    for (int m = 32; m; m >>= 1) vs += __shfl_xor(vs, m);
    float inv = 1.f / sqrtf(vs * (1.f / 128.f) + 1e-5f);
    outV[(size_t)i*128 + t]  = d0 * inv * g[t]  + be[t];
    outV[(size_t)i*128 + t2] = d1 * inv * g[t2] + be[t2];
}

// ---------------- fused edge features + bf16 MFMA GEMM + LN ----------------
// 32 edges/block, 8 waves = (egrp in {0,1}) x (ks in {0..3} K-split).
// 4 chunk-streams double-buffered in LDS (one per ks), staged block-wide by
// global_load_lds; per step: __syncthreads -> issue next batch (safe: all
// readers of the target buffer passed the barrier) -> compute. 1-step prefetch
// lead covers L2 latency, so the barrier's vmcnt drain finds counter empty.
// K-partials reduced via LDS scratch (stream buffers reused after a barrier).
__global__ __launch_bounds__(512) void k_edge(const float* __restrict__ Xa, const int* __restrict__ Eidx,
                                              const unsigned short* __restrict__ Wt,
                                              const float* __restrict__ ebias, const float* __restrict__ egain,
                                              const float* __restrict__ ebeta,
                                              float* __restrict__ outE, int N) {
    __shared__ __align__(16) unsigned short sB[KSPL][2][4096];  // 64 KB stream buffers
    __shared__ unsigned short sDh[EPB * 200];                   // bf16 D table, 12.8 KB
    __shared__ float sDpe[EPB];
    const int NE = N * TOPK;
    int t = threadIdx.x;                 // 0..511
    int geBase = blockIdx.x * EPB;
    int ln = t & 63, wid = t >> 6;
    int egrp = wid & 1, ks = wid >> 1;
    int base = ks * SMAX;
    int cnt = (ks < 3) ? SMAX : (NCHUNK - 3 * SMAX);   // 25,25,25,24

    // block-wide staging: thread t covers stream chunk's LDS elems t*8..t*8+8
    // <=> koff = t>>7, col = t&127; src = Wt[col][chunk*32 + koff*8]
    const unsigned short* gSrc = Wt + (size_t)(t & 127) * KPAD + (t >> 7) * 8;

    // prologue: stage chunk (base_st + 0) of every stream into parity 0
#pragma unroll
    for (int st = 0; st < KSPL; st++) {
        const unsigned short* src = gSrc + (size_t)(st * SMAX) * 32;
        __builtin_amdgcn_global_load_lds((gptr_t)(const void*)src,
                                         (lptr_t)(void*)(&sB[st][0][(size_t)t * 8]), 16, 0, 0);
    }

    // D-table build: 16 threads per edge
    {
        int le = t >> 4, q = t & 15;
        int ge = geBase + le; if (ge >= NE) ge = NE - 1;
        int i = ge / TOPK;
        int j = Eidx[ge];
        if (q == 0) sDpe[le] = (float)j - (float)i;
        const float* Xi = Xa + (size_t)i * NAT * 3;
        const float* Xj = Xa + (size_t)j * NAT * 3;
        for (int p = q; p < 196; p += 16) {
            int a = p / 14, b = p - 14 * a;
            float dx = Xi[a*3+0] - Xj[b*3+0];
            float dy = Xi[a*3+1] - Xj[b*3+1];
            float dz = Xi[a*3+2] - Xj[b*3+2];
            sDh[le * 200 + p] = f2bf(sqrtf(dx*dx + dy*dy + dz*dz + 1e-6f));
        }
    }

    int lrow = ln & 15, koff = ln >> 4;
    int leA = egrp * 16 + lrow;           // this lane's A-row (edge)
    const unsigned short* sDrow = sDh + (size_t)leA * 200;
    float dpe = 0.f;

    f32x4 acc[8];
#pragma unroll
    for (int f = 0; f < 8; f++) acc[f] = (f32x4){0.f, 0.f, 0.f, 0.f};

    for (int s = 0; s < SMAX; s++) {
        __syncthreads();                   // batch(s) landed (vmcnt drain) + all reads of parity (s+1)&1 done

        // stage chunk base_st + s+1 of each stream into parity (s+1)&1
#pragma unroll
        for (int st = 0; st < KSPL; st++) {
            int cst = (st < 3) ? SMAX : (NCHUNK - 3 * SMAX);
            if (s + 1 < cst) {
                const unsigned short* src = gSrc + (size_t)(st * SMAX + s + 1) * 32;
                __builtin_amdgcn_global_load_lds((gptr_t)(const void*)src,
                                                 (lptr_t)(void*)(&sB[st][(s + 1) & 1][(size_t)t * 8]), 16, 0, 0);
            }
        }

        if (s >= cnt) continue;            // only ks=3 @ s=24 (no barrier below)
        if (s == 0) dpe = sDpe[leA];

        int kc = base + s;
        int kb = kc * 32 + koff * 8;
        bf16x8 afrag;
        if (kb < 16) {
#pragma unroll
            for (int jj = 0; jj < 8; jj++) {
                float fr = __expf(-1.1512925f * (float)jj);   // 10000^(-2m/16)
                float ang = dpe * fr;
                afrag[jj] = cvtbf((kb == 0) ? cosf(ang) : sinf(ang));
            }
        } else if (kb >= EDGE_IN) {
#pragma unroll
            for (int jj = 0; jj < 8; jj++) afrag[jj] = 0;
        } else {
            int pk = kb - 16;              // 8 consecutive k never cross a pair
            float D = bf2f(sDrow[pk >> 4]);
            float bse = (float)(pk & 15);
#pragma unroll
            for (int jj = 0; jj < 8; jj++) {
                float mu = (bse + (float)jj) * 1.3333334f;    // linspace(0,20,16)
                float tt = (D - mu) * 0.8f;                   // /1.25
                afrag[jj] = cvtbf(__expf(-tt * tt));
            }
        }

        const unsigned short* bbuf = &sB[ks][s & 1][0];
#pragma unroll
        for (int f = 0; f < 8; f++) {
            bf16x8 bfrag = *reinterpret_cast<const bf16x8*>(bbuf + ((size_t)koff * 128 + f * 16 + lrow) * 8);
            acc[f] = __builtin_amdgcn_mfma_f32_16x16x32_bf16(afrag, bfrag, acc[f], 0, 0, 0);
        }
    }

    // ---- K-split reduction: ks 1..3 partials -> ks 0, via sB reused as scratch ----
    __syncthreads();                       // all compute done; sB free to alias
    f32x4* scr = reinterpret_cast<f32x4*>(&sB[0][0][0]);   // 4096 slots, need 3072
    if (ks > 0) {
#pragma unroll
        for (int f = 0; f < 8; f++)
            scr[((size_t)(ks - 1) * 2 + egrp) * 512 + f * 64 + ln] = acc[f];
    }
    __syncthreads();
    if (ks > 0) return;
#pragma unroll
    for (int f = 0; f < 8; f++) {
#pragma unroll
        for (int sr = 0; sr < 3; sr++) {
            f32x4 o = scr[((size_t)sr * 2 + egrp) * 512 + f * 64 + ln];
            acc[f][0] += o[0]; acc[f][1] += o[1]; acc[f][2] += o[2]; acc[f][3] += o[3];
        }
    }

    // epilogue: +bias, LN over 128 cols (reduce across 16-lane group), f32 store
    float gg[8], bb2[8], eb[8];
#pragma unroll
    for (int f = 0; f < 8; f++) { int c = f * 16 + lrow; gg[f] = egain[c]; bb2[f] = ebeta[c]; eb[f] = ebias[c]; }
#pragma unroll
    for (int r = 0; r < 4; r++) {
        float x[8], sum = 0.f;
#pragma unroll
        for (int f = 0; f < 8; f++) { x[f] = acc[f][r] + eb[f]; sum += x[f]; }
#pragma unroll
        for (int m = 1; m < 16; m <<= 1) sum += __shfl_xor(sum, m);
        float mean = sum * (1.f / 128.f);
        float vs = 0.f;
#pragma unroll
        for (int f = 0; f < 8; f++) { float d2 = x[f] - mean; vs += d2 * d2; }
#pragma unroll
        for (int m = 1; m < 16; m <<= 1) vs += __shfl_xor(vs, m);
        float inv = 1.f / sqrtf(vs * (1.f / 128.f) + 1e-5f);
        int row = geBase + egrp * 16 + koff * 4 + r;
        if (row < NE) {
            float* po = outE + (size_t)row * 128 + lrow;
#pragma unroll
            for (int f = 0; f < 8; f++) po[f * 16] = (x[f] - mean) * inv * gg[f] + bb2[f];
        }
    }
}

extern "C" void kernel_launch(void* const* d_in, const int* in_sizes, int n_in,
                              void* d_out, int out_size, void* d_ws, size_t ws_size,
                              hipStream_t stream) {
    const float* X       = (const float*)d_in[0];
    const int*   S       = (const int*)d_in[1];
    const float* BB      = (const float*)d_in[2];
    const float* mask    = (const float*)d_in[3];
    const float* node_w  = (const float*)d_in[4];
    const float* node_b  = (const float*)d_in[5];
    const float* node_g  = (const float*)d_in[6];
    const float* node_lb = (const float*)d_in[7];
    const float* edge_w  = (const float*)d_in[8];
    const float* edge_b  = (const float*)d_in[9];
    const float* edge_g  = (const float*)d_in[10];
    const float* edge_lb = (const float*)d_in[11];
    int N  = in_sizes[1];       // 1024
    int NE = N * TOPK;

    float* out  = (float*)d_out;
    float* outV = out;                                  // N*128 f32
    float* outE = out + (size_t)N * 128;                // NE*128 f32
    float* outI = outE + (size_t)NE * 128;              // NE f32

    char* ws = (char*)d_ws;
    int* Eidx = (int*)ws;
    size_t off = ((size_t)NE * 4 + 255) & ~(size_t)255;
    float* Xa = (float*)(ws + off);
    off += (((size_t)N * NAT * 3 * 4) + 255) & ~(size_t)255;
    unsigned short* Wt = (unsigned short*)(ws + off);   // 128*KPAD bf16

    k_prep<<<dim3((N + 255) / 256), dim3(256), 0, stream>>>(X, Xa, N);
    k_wt<<<dim3(KPAD / 32, 128 / 32), dim3(32, 8), 0, stream>>>(edge_w, Wt);
    k_knn<<<dim3(N), dim3(256), 0, stream>>>(X, mask, Eidx, outI, N);
    k_node<<<dim3(N), dim3(64), 0, stream>>>(S, BB, node_w, node_b, node_g, node_lb, outV, N);
    k_edge<<<dim3((NE + EPB - 1) / EPB), dim3(512), 0, stream>>>(Xa, Eidx, Wt, edge_b, edge_g, edge_lb, outE, N);
}

// Round 10
// 152.808 us; speedup vs baseline: 1.4893x; 1.4893x over previous
//
#include <hip/hip_runtime.h>
#include <hip/hip_bf16.h>

#define TOPK 30
#define NAT 14
#define EDGE_IN 3152   // 16 PE + 14*14*16 RBF
#define NCHUNK 99      // K chunks of 32 (3168 padded)
#define EPB 32         // edges per k_edge block (one wave, M=32)

typedef __attribute__((ext_vector_type(8))) short bf16x8;
typedef __attribute__((ext_vector_type(4))) float f32x4;

__device__ __forceinline__ unsigned short f2bf(float f) {
    union { float f; unsigned u; } v; v.f = f;
    unsigned r = v.u + 0x7FFF + ((v.u >> 16) & 1);   // RNE
    return (unsigned short)(r >> 16);
}
__device__ __forceinline__ float bf2f(unsigned short h) {
    union { unsigned u; float f; } v; v.u = ((unsigned)h) << 16;
    return v.f;
}
__device__ __forceinline__ short cvtbf(float f) {
    __hip_bfloat16 h = __float2bfloat16(f);
    return *reinterpret_cast<short*>(&h);
}

// ---------------- Xa = [N, Ca, C, O, Cb, sc9] ----------------
__global__ void k_prep(const float* __restrict__ X, float* __restrict__ Xa, int N) {
    int i = blockIdx.x * blockDim.x + threadIdx.x;
    if (i >= N) return;
    const float* xi = X + (size_t)i * NAT * 3;
    float* xo = Xa + (size_t)i * NAT * 3;
    float Nx = xi[0], Ny = xi[1], Nz = xi[2];
    float Ax = xi[3], Ay = xi[4], Az = xi[5];
    float Cx = xi[6], Cy = xi[7], Cz = xi[8];
    float bx = Ax - Nx, by = Ay - Ny, bz = Az - Nz;
    float cx = Cx - Ax, cy = Cy - Ay, cz = Cz - Az;
    float ax = by * cz - bz * cy;
    float ay = bz * cx - bx * cz;
    float az = bx * cy - by * cx;
    float Cbx = -0.58273431f * ax + 0.56802827f * bx - 0.54067466f * cx + Ax;
    float Cby = -0.58273431f * ay + 0.56802827f * by - 0.54067466f * cy + Ay;
    float Cbz = -0.58273431f * az + 0.56802827f * bz - 0.54067466f * cz + Az;
#pragma unroll
    for (int a = 0; a < 4; a++) { xo[a*3] = xi[a*3]; xo[a*3+1] = xi[a*3+1]; xo[a*3+2] = xi[a*3+2]; }
    xo[12] = Cbx; xo[13] = Cby; xo[14] = Cbz;
#pragma unroll
    for (int a = 5; a < 14; a++) { xo[a*3] = xi[a*3]; xo[a*3+1] = xi[a*3+1]; xo[a*3+2] = xi[a*3+2]; }
}

// ---------------- Wt2: W packed in MFMA-fragment order ----------------
// Wt2[((kc*8+f)*64 + ln)*8 + e] = bf16(W[k][c]), k = kc*32+(ln>>4)*8+e, c = f*16+(ln&15)
// -> in k_edge, fragment (kc,f) is one coalesced 1KB wave-load at lane offset ln*8.
__global__ void k_wt2(const float* __restrict__ W, unsigned short* __restrict__ Wt2) {
    int gid = blockIdx.x * 256 + threadIdx.x;     // one fragment slice per thread
    if (gid >= NCHUNK * 8 * 64) return;
    int ln = gid & 63;
    int kcf = gid >> 6;
    int kc = kcf >> 3, f = kcf & 7;
    int c = f * 16 + (ln & 15);
    int k0 = kc * 32 + (ln >> 4) * 8;
    bf16x8 o;
#pragma unroll
    for (int e = 0; e < 8; e++) {
        int k = k0 + e;
        float v = (k < EDGE_IN) ? W[(size_t)k * 128 + c] : 0.f;
        o[e] = (short)f2bf(v);
    }
    *reinterpret_cast<bf16x8*>(Wt2 + (size_t)gid * 8) = o;
}

// ---------------- exact stable KNN in FLOAT64 (proven r3-r8 version) ----------------
__global__ __launch_bounds__(256) void k_knn(const float* __restrict__ X, const float* __restrict__ mask,
                                             int* __restrict__ Eidx, float* __restrict__ outI, int N) {
    __shared__ double sD[1024];
    __shared__ double sMax[4];
    __shared__ double sBd[4];
    __shared__ int    sBi[4];
    int i = blockIdx.x, t = threadIdx.x;
    double mi = (double)mask[i];
    double xx = (double)X[((size_t)i * NAT + 1) * 3 + 0];
    double xy = (double)X[((size_t)i * NAT + 1) * 3 + 1];
    double xz = (double)X[((size_t)i * NAT + 1) * 3 + 2];
    double lmax = -1.0;
    for (int j = t; j < N; j += 256) {
        double dx = xx - (double)X[((size_t)j * NAT + 1) * 3 + 0];
        double dy = xy - (double)X[((size_t)j * NAT + 1) * 3 + 1];
        double dz = xz - (double)X[((size_t)j * NAT + 1) * 3 + 2];
        double s = ((dx * dx + dy * dy) + dz * dz) + 1e-6;
        double d = (mi * (double)mask[j]) * sqrt(s);
        sD[j] = d;
        lmax = fmax(lmax, d);
    }
#pragma unroll
    for (int m = 32; m; m >>= 1) lmax = fmax(lmax, __shfl_xor(lmax, m));
    if ((t & 63) == 0) sMax[t >> 6] = lmax;
    __syncthreads();
    double Dmax = fmax(fmax(sMax[0], sMax[1]), fmax(sMax[2], sMax[3]));
    for (int j = t; j < N; j += 256) {
        double m2 = mi * (double)mask[j];
        sD[j] = sD[j] + 2.0 * (1.0 - m2) * Dmax;
    }
    __syncthreads();
    for (int s = 0; s < TOPK; s++) {
        double bd = 1e300;
        int bi = 0x7FFFFFFF;
        for (int j = t; j < N; j += 256) {
            double d = sD[j];
            if (d < bd || (d == bd && j < bi)) { bd = d; bi = j; }
        }
#pragma unroll
        for (int m = 32; m; m >>= 1) {
            double od = __shfl_xor(bd, m);
            int oi = __shfl_xor(bi, m);
            if (od < bd || (od == bd && oi < bi)) { bd = od; bi = oi; }
        }
        if ((t & 63) == 0) { sBd[t >> 6] = bd; sBi[t >> 6] = bi; }
        __syncthreads();
        if (t == 0) {
            double d0 = sBd[0]; int i0 = sBi[0];
#pragma unroll
            for (int w = 1; w < 4; w++) {
                if (sBd[w] < d0 || (sBd[w] == d0 && sBi[w] < i0)) { d0 = sBd[w]; i0 = sBi[w]; }
            }
            Eidx[(size_t)i * TOPK + s] = i0;
            outI[(size_t)i * TOPK + s] = (float)i0;
            sD[i0] = 1e300;
        }
        __syncthreads();
    }
}

// ---------------- node: onehot-gather + matvec + LN (one wave per residue) ----------------
__global__ __launch_bounds__(64) void k_node(const int* __restrict__ S, const float* __restrict__ BB,
                                             const float* __restrict__ W, const float* __restrict__ nb,
                                             const float* __restrict__ g, const float* __restrict__ be,
                                             float* __restrict__ outV, int N) {
    int i = blockIdx.x, t = threadIdx.x;
    int s = S[i];
    float b0 = BB[i*6], b1 = BB[i*6+1], b2 = BB[i*6+2], b3 = BB[i*6+3], b4 = BB[i*6+4], b5 = BB[i*6+5];
    int t2 = t + 64;
    float x0 = W[(size_t)s*128 + t] + nb[t]
             + b0*W[21*128+t] + b1*W[22*128+t] + b2*W[23*128+t]
             + b3*W[24*128+t] + b4*W[25*128+t] + b5*W[26*128+t];
    float x1 = W[(size_t)s*128 + t2] + nb[t2]
             + b0*W[21*128+t2] + b1*W[22*128+t2] + b2*W[23*128+t2]
             + b3*W[24*128+t2] + b4*W[25*128+t2] + b5*W[26*128+t2];
    float sum = x0 + x1;
#pragma unroll
    for (int m = 32; m; m >>= 1) sum += __shfl_xor(sum, m);
    float mean = sum * (1.f / 128.f);
    float d0 = x0 - mean, d1 = x1 - mean;
    float vs = d0*d0 + d1*d1;
#pragma unroll
    for (int m = 32; m; m >>= 1) vs += __shfl_xor(vs, m);
    float inv = 1.f / sqrtf(vs * (1.f / 128.f) + 1e-5f);
    outV[(size_t)i*128 + t]  = d0 * inv * g[t]  + be[t];
    outV[(size_t)i*128 + t2] = d1 * inv * g[t2] + be[t2];
}

// ---------------- A-fragment generator (PE / RBF / pad) ----------------
__device__ __forceinline__ bf16x8 gen_afrag(int kb, float dpe, const unsigned short* __restrict__ sDrow) {
    const float FR[8] = {1.0f, 0.31622776601683794f, 0.1f, 0.03162277660168379f,
                         0.01f, 0.0031622776601683794f, 0.001f, 0.00031622776601683794f};
    bf16x8 a;
    if (kb < 16) {
#pragma unroll
        for (int jj = 0; jj < 8; jj++) {
            float ang = dpe * FR[jj];
            a[jj] = cvtbf((kb == 0) ? cosf(ang) : sinf(ang));
        }
    } else if (kb >= EDGE_IN) {
#pragma unroll
        for (int jj = 0; jj < 8; jj++) a[jj] = 0;
    } else {
        int pk = kb - 16;                 // 8 consecutive k never cross a pair
        float D = bf2f(sDrow[pk >> 4]);
        float base = (float)(pk & 15);
#pragma unroll
        for (int jj = 0; jj < 8; jj++) {
            float mu = (base + (float)jj) * 1.3333334f;   // linspace(0,20,16)
            float tt = (D - mu) * 0.8f;                   // /1.25
            a[jj] = cvtbf(__expf(-tt * tt));
        }
    }
    return a;
}

// ---------------- fused edge features + bf16 MFMA GEMM + LN ----------------
// ONE WAVE per block, 32 edges (M=32). B fragments read straight from the
// fragment-ordered Wt2 (coalesced 1KB wave-loads) into a register ping-pong
// (bA/bB, unroll-2) — no B LDS, no barriers, no inline waits. LDS = 13KB ->
// ~12 blocks/CU = 3 waves/SIMD of fully independent pipelines.
__global__ __launch_bounds__(64) void k_edge(const float* __restrict__ Xa, const int* __restrict__ Eidx,
                                             const unsigned short* __restrict__ Wt2,
                                             const float* __restrict__ ebias, const float* __restrict__ egain,
                                             const float* __restrict__ ebeta,
                                             float* __restrict__ outE, int N) {
    __shared__ unsigned short sDh[EPB * 200];            // bf16 D table, 12.8 KB
    __shared__ float sDpe[EPB];
    const int NE = N * TOPK;
    int t = threadIdx.x;                 // 0..63, one wave
    int geBase = blockIdx.x * EPB;

    const unsigned short* gB = Wt2 + (size_t)t * 8;      // lane fragment base
    // fragment (kc,f) at gB + (kc*8+f)*512

    // prologue: issue chunk-0 B loads first so they fly under the D-table build
    bf16x8 bA[8], bB[8];
#pragma unroll
    for (int f = 0; f < 8; f++)
        bA[f] = *reinterpret_cast<const bf16x8*>(gB + (size_t)f * 512);

    // D-table build: 2 threads per edge, 98 pair-distances each
    {
        int le = t >> 1, q = t & 1;
        int ge = geBase + le; if (ge >= NE) ge = NE - 1;
        int i = ge / TOPK;
        int j = Eidx[ge];
        if (q == 0) sDpe[le] = (float)j - (float)i;
        const float* Xi = Xa + (size_t)i * NAT * 3;
        const float* Xj = Xa + (size_t)j * NAT * 3;
        for (int p = q; p < 196; p += 2) {
            int a = p / 14, b = p - 14 * a;
            float dx = Xi[a*3+0] - Xj[b*3+0];
            float dy = Xi[a*3+1] - Xj[b*3+1];
            float dz = Xi[a*3+2] - Xj[b*3+2];
            sDh[le * 200 + p] = f2bf(sqrtf(dx*dx + dy*dy + dz*dz + 1e-6f));
        }
    }
    asm volatile("s_waitcnt lgkmcnt(0)" ::: "memory");   // single wave: our ds_writes done

    int lrow = t & 15, koff = t >> 4;
    const unsigned short* sDrow0 = sDh + (size_t)lrow * 200;
    const unsigned short* sDrow1 = sDh + (size_t)(lrow + 16) * 200;
    float dpe0 = sDpe[lrow];
    float dpe1 = sDpe[lrow + 16];

    f32x4 acc0[8], acc1[8];
#pragma unroll
    for (int f = 0; f < 8; f++) { acc0[f] = (f32x4){0.f,0.f,0.f,0.f}; acc1[f] = (f32x4){0.f,0.f,0.f,0.f}; }

    for (int kc = 0; kc < NCHUNK; kc += 2) {
        // prefetch kc+1 into bB
        if (kc + 1 < NCHUNK) {
#pragma unroll
            for (int f = 0; f < 8; f++)
                bB[f] = *reinterpret_cast<const bf16x8*>(gB + ((size_t)(kc + 1) * 8 + f) * 512);
        }
        {
            int kb = kc * 32 + koff * 8;
            bf16x8 af0 = gen_afrag(kb, dpe0, sDrow0);
            bf16x8 af1 = gen_afrag(kb, dpe1, sDrow1);
#pragma unroll
            for (int f = 0; f < 8; f++) {
                acc0[f] = __builtin_amdgcn_mfma_f32_16x16x32_bf16(af0, bA[f], acc0[f], 0, 0, 0);
                acc1[f] = __builtin_amdgcn_mfma_f32_16x16x32_bf16(af1, bA[f], acc1[f], 0, 0, 0);
            }
        }
        // prefetch kc+2 into bA
        if (kc + 2 < NCHUNK) {
#pragma unroll
            for (int f = 0; f < 8; f++)
                bA[f] = *reinterpret_cast<const bf16x8*>(gB + ((size_t)(kc + 2) * 8 + f) * 512);
        }
        if (kc + 1 < NCHUNK) {
            int kb = (kc + 1) * 32 + koff * 8;
            bf16x8 af0 = gen_afrag(kb, dpe0, sDrow0);
            bf16x8 af1 = gen_afrag(kb, dpe1, sDrow1);
#pragma unroll
            for (int f = 0; f < 8; f++) {
                acc0[f] = __builtin_amdgcn_mfma_f32_16x16x32_bf16(af0, bB[f], acc0[f], 0, 0, 0);
                acc1[f] = __builtin_amdgcn_mfma_f32_16x16x32_bf16(af1, bB[f], acc1[f], 0, 0, 0);
            }
        }
    }

    // epilogue: +bias, LN over 128 cols (reduce across the 16-lane column group), f32 store
    float gg[8], bb2[8], eb[8];
#pragma unroll
    for (int f = 0; f < 8; f++) { int c = f * 16 + lrow; gg[f] = egain[c]; bb2[f] = ebeta[c]; eb[f] = ebias[c]; }
#pragma unroll
    for (int g2 = 0; g2 < 2; g2++) {
#pragma unroll
        for (int r = 0; r < 4; r++) {
            float x[8], sum = 0.f;
#pragma unroll
            for (int f = 0; f < 8; f++) {
                float v = (g2 ? acc1[f][r] : acc0[f][r]) + eb[f];
                x[f] = v; sum += v;
            }
#pragma unroll
            for (int m = 1; m < 16; m <<= 1) sum += __shfl_xor(sum, m);
            float mean = sum * (1.f / 128.f);
            float vs = 0.f;
#pragma unroll
            for (int f = 0; f < 8; f++) { float d2 = x[f] - mean; vs += d2 * d2; }
#pragma unroll
            for (int m = 1; m < 16; m <<= 1) vs += __shfl_xor(vs, m);
            float inv = 1.f / sqrtf(vs * (1.f / 128.f) + 1e-5f);
            int row = geBase + g2 * 16 + koff * 4 + r;
            if (row < NE) {
                float* po = outE + (size_t)row * 128 + lrow;
#pragma unroll
                for (int f = 0; f < 8; f++) po[f * 16] = (x[f] - mean) * inv * gg[f] + bb2[f];
            }
        }
    }
}

extern "C" void kernel_launch(void* const* d_in, const int* in_sizes, int n_in,
                              void* d_out, int out_size, void* d_ws, size_t ws_size,
                              hipStream_t stream) {
    const float* X       = (const float*)d_in[0];
    const int*   S       = (const int*)d_in[1];
    const float* BB      = (const float*)d_in[2];
    const float* mask    = (const float*)d_in[3];
    const float* node_w  = (const float*)d_in[4];
    const float* node_b  = (const float*)d_in[5];
    const float* node_g  = (const float*)d_in[6];
    const float* node_lb = (const float*)d_in[7];
    const float* edge_w  = (const float*)d_in[8];
    const float* edge_b  = (const float*)d_in[9];
    const float* edge_g  = (const float*)d_in[10];
    const float* edge_lb = (const float*)d_in[11];
    int N  = in_sizes[1];       // 1024
    int NE = N * TOPK;

    float* out  = (float*)d_out;
    float* outV = out;                                  // N*128 f32
    float* outE = out + (size_t)N * 128;                // NE*128 f32
    float* outI = outE + (size_t)NE * 128;              // NE f32

    char* ws = (char*)d_ws;
    int* Eidx = (int*)ws;
    size_t off = ((size_t)NE * 4 + 255) & ~(size_t)255;
    float* Xa = (float*)(ws + off);
    off += (((size_t)N * NAT * 3 * 4) + 255) & ~(size_t)255;
    unsigned short* Wt2 = (unsigned short*)(ws + off);  // NCHUNK*8*64*8 bf16 = 811008 B

    k_prep<<<dim3((N + 255) / 256), dim3(256), 0, stream>>>(X, Xa, N);
    k_wt2<<<dim3((NCHUNK * 8 * 64 + 255) / 256), dim3(256), 0, stream>>>(edge_w, Wt2);
    k_knn<<<dim3(N), dim3(256), 0, stream>>>(X, mask, Eidx, outI, N);
    k_node<<<dim3(N), dim3(64), 0, stream>>>(S, BB, node_w, node_b, node_g, node_lb, outV, N);
    k_edge<<<dim3((NE + EPB - 1) / EPB), dim3(64), 0, stream>>>(Xa, Eidx, Wt2, edge_b, edge_g, edge_lb, outE, N);
}